// Round 1
// baseline (320.886 us; speedup 1.0000x reference)
//
#include <hip/hip_runtime.h>

constexpr int NB = 128;   // batch
constexpr int NS = 512;   // seq len
constexpr int NH = 768;   // hidden
constexpr int NT = 3;     // tags
constexpr int ROWS = NB * NS;      // 65536
constexpr int NCH = 64;            // chunks per sequence
constexpr int CHL = 8;             // steps per chunk
constexpr float NEG = -1e30f;

__device__ __forceinline__ float lse3(float x0, float x1, float x2) {
    float m = fmaxf(x0, fmaxf(x1, x2));
    return m + __logf(__expf(x0 - m) + __expf(x1 - m) + __expf(x2 - m));
}

__device__ __forceinline__ float dot4(float4 a, float4 b) {
    return a.x * b.x + a.y * b.y + a.z * b.z + a.w * b.w;
}

__device__ __forceinline__ float sel3(int t, float a, float b, float c) {
    return (t == 0) ? a : ((t == 1) ? b : c);
}

// prediction[b,s,t] = dot(inputs[b,s,:], W[t,:]) + b[t]
// One wave per 2 rows per iteration: 6 outstanding float4 loads/lane,
// packed butterfly reduction (17 shuffles/iter instead of 36).
// W held in registers (9 float4).
__global__ __launch_bounds__(256) void pred_kernel(
    const float* __restrict__ x, const float* __restrict__ W,
    const float* __restrict__ bias, float* __restrict__ out)
{
    const int lane = threadIdx.x & 63;
    const int gw   = blockIdx.x * 4 + (threadIdx.x >> 6);
    const int nw   = gridDim.x * 4;          // 4096 waves
    const int stride = nw * 2;               // rows per sweep

    const float4* W4 = (const float4*)W;
    float4 w[3][3];
#pragma unroll
    for (int t = 0; t < 3; ++t)
#pragma unroll
        for (int c = 0; c < 3; ++c)
            w[t][c] = W4[t * 192 + c * 64 + lane];
    const float b0 = bias[0], b1 = bias[1], b2 = bias[2];

    const float4* X4 = (const float4*)x;
    int row = gw * 2;
    if (row >= ROWS) return;

    float4 vA[3], vB[3];
    {
        const int ba = row * 192 + lane;
#pragma unroll
        for (int c = 0; c < 3; ++c) { vA[c] = X4[ba + c * 64]; vB[c] = X4[ba + 192 + c * 64]; }
    }

    while (true) {
        const int nrow = row + stride;
        const bool more = nrow < ROWS;
        float4 tA[3], tB[3];
        if (more) {
            const int nb = nrow * 192 + lane;
#pragma unroll
            for (int c = 0; c < 3; ++c) { tA[c] = X4[nb + c * 64]; tB[c] = X4[nb + 192 + c * 64]; }
        }
        float a0 = dot4(vA[0], w[0][0]) + dot4(vA[1], w[0][1]) + dot4(vA[2], w[0][2]);
        float a1 = dot4(vA[0], w[1][0]) + dot4(vA[1], w[1][1]) + dot4(vA[2], w[1][2]);
        float a2 = dot4(vA[0], w[2][0]) + dot4(vA[1], w[2][1]) + dot4(vA[2], w[2][2]);
        float c0 = dot4(vB[0], w[0][0]) + dot4(vB[1], w[0][1]) + dot4(vB[2], w[0][2]);
        float c1 = dot4(vB[0], w[1][0]) + dot4(vB[1], w[1][1]) + dot4(vB[2], w[1][2]);
        float c2 = dot4(vB[0], w[2][0]) + dot4(vB[1], w[2][1]) + dot4(vB[2], w[2][2]);

        // Packed reduction. Pair i = (a_i over rowA, c_i over rowB).
        // Stage-32 fold: every lane holds pairwise sum l + (l^32); the low
        // half keeps the a-value, high half the c-value.
        float r0 = a0 + __shfl_xor(a0, 32, 64);
        float s0 = c0 + __shfl_xor(c0, 32, 64);
        float w0 = (lane & 32) ? s0 : r0;
        float r1 = a1 + __shfl_xor(a1, 32, 64);
        float s1 = c1 + __shfl_xor(c1, 32, 64);
        float w1 = (lane & 32) ? s1 : r1;
        float r2 = a2 + __shfl_xor(a2, 32, 64);
        float s2 = c2 + __shfl_xor(c2, 32, 64);
        float w2 = (lane & 32) ? s2 : r2;
        // Stage-16 fold packs w0/w1 into quadrants of z:
        // lanes 0-15: a0, 16-31: a1, 32-47: c0, 48-63: c1.
        float p0 = w0 + __shfl_xor(w0, 16, 64);
        float p1 = w1 + __shfl_xor(w1, 16, 64);
        float z  = (lane & 16) ? p1 : p0;
#pragma unroll
        for (int off = 8; off >= 1; off >>= 1)
            z += __shfl_xor(z, off, 64);
        // w2 reduces over the remaining 5 levels: lanes 0-31: a2, 32-63: c2.
#pragma unroll
        for (int off = 16; off >= 1; off >>= 1)
            w2 += __shfl_xor(w2, off, 64);

        if ((lane & 15) == 0) {
            const int t = (lane >> 4) & 1;   // 0 or 1 (tag index)
            const int r = lane >> 5;         // 0: row, 1: row+1
            out[(size_t)row * 3 + r * 3 + t] = z + ((t == 0) ? b0 : b1);
        }
        if ((lane & 31) == 0) {
            const int r = lane >> 5;
            out[(size_t)row * 3 + r * 3 + 2] = w2 + b2;
        }
        if (!more) break;
#pragma unroll
        for (int c = 0; c < 3; ++c) { vA[c] = tA[c]; vB[c] = tB[c]; }
        row = nrow;
    }
}

// Stage A: per (batch, chunk, init-state e): chunk transfer-matrix row +
// per-chunk gold-path partial score. Bulk register loads, no latency chain.
__global__ __launch_bounds__(256) void crf_scan_kernel(
    const float* __restrict__ feats, const int* __restrict__ y,
    const float* __restrict__ trans, float* __restrict__ ws_m,
    float* __restrict__ ws_p)
{
    __shared__ float sTr[9];
    if (threadIdx.x < 9) sTr[threadIdx.x] = trans[threadIdx.x];
    __syncthreads();

    const int gtid = blockIdx.x * 256 + threadIdx.x;   // < 128*64*3
    const int e  = gtid % 3;
    const int bc = gtid / 3;
    const int b  = bc >> 6;
    const int c  = bc & 63;

    const float T00 = sTr[0], T01 = sTr[1], T02 = sTr[2];
    const float T10 = sTr[3], T11 = sTr[4], T12 = sTr[5];
    const float T20 = sTr[6], T21 = sTr[7], T22 = sTr[8];

    const float* fb = feats + (size_t)b * NS * NT;
    const int*   yb = y + b * NS;

    // Bulk load: 24 feats (6 float4, 16B-aligned: c*96B) + 8 tags (2 int4)
    float ff[24];
    {
        float4* fv = (float4*)ff;
        const float4* src = (const float4*)(fb + c * CHL * NT);
#pragma unroll
        for (int i = 0; i < 6; ++i) fv[i] = src[i];
    }
    int yy[8];
    {
        int4* yv = (int4*)yy;
        const int4* ys = (const int4*)(yb + c * CHL);
        yv[0] = ys[0]; yv[1] = ys[1];
    }

    float a0 = (e == 0) ? 0.f : NEG;
    float a1 = (e == 1) ? 0.f : NEG;
    float a2 = (e == 2) ? 0.f : NEG;

    float sc = 0.f;
    int prev;
    if (c == 0) {
        prev = yy[0];
        sc = sel3(prev, ff[0], ff[1], ff[2]);   // emit at s=0
    } else {
        prev = yb[c * CHL - 1];
    }
    const int sl0 = (c == 0) ? 1 : 0;

#pragma unroll
    for (int sl = 0; sl < CHL; ++sl) {
        if (sl < sl0) continue;
        const float f0 = ff[sl * 3], f1 = ff[sl * 3 + 1], f2 = ff[sl * 3 + 2];
        const int tg = yy[sl];
        sc += sel3(tg, f0, f1, f2) + sTr[prev * 3 + tg];
        prev = tg;
        const float n0 = f0 + lse3(a0 + T00, a1 + T10, a2 + T20);
        const float n1 = f1 + lse3(a0 + T01, a1 + T11, a2 + T21);
        const float n2 = f2 + lse3(a0 + T02, a1 + T12, a2 + T22);
        a0 = n0; a1 = n1; a2 = n2;
    }

    float4* dst = (float4*)(ws_m + (size_t)(b * NCH + c) * 12) + e;
    *dst = make_float4(a0, a1, a2, 0.f);
    if (e == 0) ws_p[b * NCH + c] = sc;
}

// Stage B: per batch, fold 64 chunk matrices into alpha, finish loss.
__global__ __launch_bounds__(128) void crf_combine_kernel(
    const float* __restrict__ feats, const int* __restrict__ y,
    const float* __restrict__ ws_m, const float* __restrict__ ws_p,
    const float* __restrict__ startt, const float* __restrict__ stopt,
    float* __restrict__ loss_out)
{
    __shared__ float partial[2];
    const int b = threadIdx.x;

    const float st0 = startt[0], st1 = startt[1], st2 = startt[2];
    const float sp0 = stopt[0],  sp1 = stopt[1],  sp2 = stopt[2];

    const float* fb = feats + (size_t)b * NS * NT;
    float a0 = fb[0] + st0, a1 = fb[1] + st1, a2 = fb[2] + st2;

    const float4* M = (const float4*)(ws_m + (size_t)b * NCH * 12);
    const float*  P = ws_p + b * NCH;

    float4 m0 = M[0], m1 = M[1], m2 = M[2];
    float  pp = P[0];
    float  sc = 0.f;

#pragma unroll 4
    for (int c = 0; c < NCH; ++c) {
        float4 u0 = m0, u1 = m1, u2 = m2; float up = pp;
        if (c < NCH - 1) {                 // prefetch next chunk
            u0 = M[(c + 1) * 3]; u1 = M[(c + 1) * 3 + 1]; u2 = M[(c + 1) * 3 + 2];
            up = P[c + 1];
        }
        sc += pp;
        const float n0 = lse3(a0 + m0.x, a1 + m1.x, a2 + m2.x);
        const float n1 = lse3(a0 + m0.y, a1 + m1.y, a2 + m2.y);
        const float n2 = lse3(a0 + m0.z, a1 + m1.z, a2 + m2.z);
        a0 = n0; a1 = n1; a2 = n2;
        m0 = u0; m1 = u1; m2 = u2; pp = up;
    }

    const float logz = lse3(a0 + sp0, a1 + sp1, a2 + sp2);
    const int y0 = y[b * NS], yl = y[b * NS + NS - 1];
    const float seq = sc + ((y0 == 0) ? st0 : ((y0 == 1) ? st1 : st2))
                         + ((yl == 0) ? sp0 : ((yl == 1) ? sp1 : sp2));
    float val = seq - logz;

#pragma unroll
    for (int off = 32; off >= 1; off >>= 1)
        val += __shfl_xor(val, off, 64);
    if ((threadIdx.x & 63) == 0) partial[threadIdx.x >> 6] = val;
    __syncthreads();
    if (threadIdx.x == 0)
        loss_out[0] = -(partial[0] + partial[1]) / (float)NB;
}

extern "C" void kernel_launch(void* const* d_in, const int* in_sizes, int n_in,
                              void* d_out, int out_size, void* d_ws, size_t ws_size,
                              hipStream_t stream)
{
    const float* x      = (const float*)d_in[0];
    const int*   y      = (const int*)d_in[1];
    const float* W      = (const float*)d_in[2];
    const float* bias   = (const float*)d_in[3];
    const float* trans  = (const float*)d_in[4];
    const float* startt = (const float*)d_in[5];
    const float* stopt  = (const float*)d_in[6];

    float* out      = (float*)d_out;
    float* loss_out = out + (size_t)NB * NS * NT;

    float* ws_m = (float*)d_ws;                        // 128*64*12 floats
    float* ws_p = ws_m + (size_t)NB * NCH * 12;

    pred_kernel<<<1024, 256, 0, stream>>>(x, W, bias, out);
    crf_scan_kernel<<<(NB * NCH * 3) / 256, 256, 0, stream>>>(out, y, trans, ws_m, ws_p);
    crf_combine_kernel<<<1, 128, 0, stream>>>(out, y, ws_m, ws_p, startt, stopt, loss_out);
}

// Round 2
// 306.174 us; speedup vs baseline: 1.0481x; 1.0481x over previous
//
#include <hip/hip_runtime.h>

constexpr int NB = 128;   // batch
constexpr int NS = 512;   // seq len
constexpr int NH = 768;   // hidden
constexpr int NT = 3;     // tags
constexpr int ROWS = NB * NS;      // 65536
constexpr int NCH = 64;            // chunks per sequence
constexpr int CHL = 8;             // steps per chunk
constexpr float NEG = -1e30f;

__device__ __forceinline__ float lse3(float x0, float x1, float x2) {
    float m = fmaxf(x0, fmaxf(x1, x2));
    return m + __logf(__expf(x0 - m) + __expf(x1 - m) + __expf(x2 - m));
}

__device__ __forceinline__ float dot4(float4 a, float4 b) {
    return a.x * b.x + a.y * b.y + a.z * b.z + a.w * b.w;
}

__device__ __forceinline__ float sel3(int t, float a, float b, float c) {
    return (t == 0) ? a : ((t == 1) ? b : c);
}

// prediction[b,s,t] = dot(inputs[b,s,:], W[t,:]) + b[t]
// One wave per 2 rows per iteration: 6 outstanding float4 loads/lane,
// packed butterfly reduction (17 shuffles/iter). W held in registers.
// Memory-bound: 201 MB read, floor ~32 us.
__global__ __launch_bounds__(256) void pred_kernel(
    const float* __restrict__ x, const float* __restrict__ W,
    const float* __restrict__ bias, float* __restrict__ out,
    float* __restrict__ loss_out)
{
    if (blockIdx.x == 0 && threadIdx.x == 0) loss_out[0] = 0.f;  // re-poisoned each iter

    const int lane = threadIdx.x & 63;
    const int gw   = blockIdx.x * 4 + (threadIdx.x >> 6);
    const int nw   = gridDim.x * 4;          // 4096 waves
    const int stride = nw * 2;               // rows per sweep

    const float4* W4 = (const float4*)W;
    float4 w[3][3];
#pragma unroll
    for (int t = 0; t < 3; ++t)
#pragma unroll
        for (int c = 0; c < 3; ++c)
            w[t][c] = W4[t * 192 + c * 64 + lane];
    const float b0 = bias[0], b1 = bias[1], b2 = bias[2];

    const float4* X4 = (const float4*)x;
    int row = gw * 2;
    if (row >= ROWS) return;

    float4 vA[3], vB[3];
    {
        const int ba = row * 192 + lane;
#pragma unroll
        for (int c = 0; c < 3; ++c) { vA[c] = X4[ba + c * 64]; vB[c] = X4[ba + 192 + c * 64]; }
    }

    while (true) {
        const int nrow = row + stride;
        const bool more = nrow < ROWS;
        float4 tA[3], tB[3];
        if (more) {
            const int nb = nrow * 192 + lane;
#pragma unroll
            for (int c = 0; c < 3; ++c) { tA[c] = X4[nb + c * 64]; tB[c] = X4[nb + 192 + c * 64]; }
        }
        float a0 = dot4(vA[0], w[0][0]) + dot4(vA[1], w[0][1]) + dot4(vA[2], w[0][2]);
        float a1 = dot4(vA[0], w[1][0]) + dot4(vA[1], w[1][1]) + dot4(vA[2], w[1][2]);
        float a2 = dot4(vA[0], w[2][0]) + dot4(vA[1], w[2][1]) + dot4(vA[2], w[2][2]);
        float c0 = dot4(vB[0], w[0][0]) + dot4(vB[1], w[0][1]) + dot4(vB[2], w[0][2]);
        float c1 = dot4(vB[0], w[1][0]) + dot4(vB[1], w[1][1]) + dot4(vB[2], w[1][2]);
        float c2 = dot4(vB[0], w[2][0]) + dot4(vB[1], w[2][1]) + dot4(vB[2], w[2][2]);

        // Packed reduction. Stage-32 fold, then pack pairs into quadrants.
        float r0 = a0 + __shfl_xor(a0, 32, 64);
        float s0 = c0 + __shfl_xor(c0, 32, 64);
        float w0 = (lane & 32) ? s0 : r0;
        float r1 = a1 + __shfl_xor(a1, 32, 64);
        float s1 = c1 + __shfl_xor(c1, 32, 64);
        float w1 = (lane & 32) ? s1 : r1;
        float r2 = a2 + __shfl_xor(a2, 32, 64);
        float s2 = c2 + __shfl_xor(c2, 32, 64);
        float w2 = (lane & 32) ? s2 : r2;
        float p0 = w0 + __shfl_xor(w0, 16, 64);
        float p1 = w1 + __shfl_xor(w1, 16, 64);
        float z  = (lane & 16) ? p1 : p0;
#pragma unroll
        for (int off = 8; off >= 1; off >>= 1)
            z += __shfl_xor(z, off, 64);
#pragma unroll
        for (int off = 16; off >= 1; off >>= 1)
            w2 += __shfl_xor(w2, off, 64);

        if ((lane & 15) == 0) {
            const int t = (lane >> 4) & 1;   // tag 0 or 1
            const int r = lane >> 5;         // 0: row, 1: row+1
            out[(size_t)row * 3 + r * 3 + t] = z + ((t == 0) ? b0 : b1);
        }
        if ((lane & 31) == 0) {
            const int r = lane >> 5;
            out[(size_t)row * 3 + r * 3 + 2] = w2 + b2;
        }
        if (!more) break;
#pragma unroll
        for (int c = 0; c < 3; ++c) { vA[c] = tA[c]; vB[c] = tB[c]; }
        row = nrow;
    }
}

// Fused CRF: one block per batch (128 blocks x 192 threads).
// Phase 1: thread (c,e) computes chunk-c transfer row for init-state e
//          (+ gold-path partial for e==0) into LDS.
// Phase 2: thread 0 folds the 64 chunk matrices serially (~0.7 us) and
//          atomicAdds the batch's loss contribution (device-scope, no
//          cross-block traffic -> no XCD coherence hazard).
__global__ __launch_bounds__(192) void crf_kernel(
    const float* __restrict__ feats, const int* __restrict__ y,
    const float* __restrict__ trans, const float* __restrict__ startt,
    const float* __restrict__ stopt, float* __restrict__ loss_out)
{
    __shared__ float  sTr[9];
    __shared__ float4 sm[NCH][3];
    __shared__ float  sp[NCH];

    const int tid = threadIdx.x;
    if (tid < 9) sTr[tid] = trans[tid];
    __syncthreads();

    const int b = blockIdx.x;
    const int e = tid % 3;
    const int c = tid / 3;

    const float T00 = sTr[0], T01 = sTr[1], T02 = sTr[2];
    const float T10 = sTr[3], T11 = sTr[4], T12 = sTr[5];
    const float T20 = sTr[6], T21 = sTr[7], T22 = sTr[8];

    const float* fb = feats + (size_t)b * NS * NT;
    const int*   yb = y + b * NS;

    // Bulk load: 24 feats (6 float4, 16B-aligned: c*96B) + 8 tags (2 int4)
    float ff[24];
    {
        float4* fv = (float4*)ff;
        const float4* src = (const float4*)(fb + c * CHL * NT);
#pragma unroll
        for (int i = 0; i < 6; ++i) fv[i] = src[i];
    }
    int yy[8];
    {
        int4* yv = (int4*)yy;
        const int4* ys = (const int4*)(yb + c * CHL);
        yv[0] = ys[0]; yv[1] = ys[1];
    }

    float a0 = (e == 0) ? 0.f : NEG;
    float a1 = (e == 1) ? 0.f : NEG;
    float a2 = (e == 2) ? 0.f : NEG;

    float sc = 0.f;
    int prev;
    if (c == 0) {
        prev = yy[0];
        sc = sel3(prev, ff[0], ff[1], ff[2]);   // emit at s=0
    } else {
        prev = yb[c * CHL - 1];
    }
    const int sl0 = (c == 0) ? 1 : 0;

#pragma unroll
    for (int sl = 0; sl < CHL; ++sl) {
        if (sl < sl0) continue;
        const float f0 = ff[sl * 3], f1 = ff[sl * 3 + 1], f2 = ff[sl * 3 + 2];
        const int tg = yy[sl];
        sc += sel3(tg, f0, f1, f2) + sTr[prev * 3 + tg];
        prev = tg;
        const float n0 = f0 + lse3(a0 + T00, a1 + T10, a2 + T20);
        const float n1 = f1 + lse3(a0 + T01, a1 + T11, a2 + T21);
        const float n2 = f2 + lse3(a0 + T02, a1 + T12, a2 + T22);
        a0 = n0; a1 = n1; a2 = n2;
    }

    sm[c][e] = make_float4(a0, a1, a2, 0.f);
    if (e == 0) sp[c] = sc;
    __syncthreads();

    if (tid == 0) {
        const float st0 = startt[0], st1 = startt[1], st2 = startt[2];
        const float sp0 = stopt[0],  sp1 = stopt[1],  sp2 = stopt[2];

        float x0 = fb[0] + st0, x1 = fb[1] + st1, x2 = fb[2] + st2;
        float sct = 0.f;
#pragma unroll 4
        for (int cc = 0; cc < NCH; ++cc) {
            const float4 m0 = sm[cc][0], m1 = sm[cc][1], m2 = sm[cc][2];
            sct += sp[cc];
            const float n0 = lse3(x0 + m0.x, x1 + m1.x, x2 + m2.x);
            const float n1 = lse3(x0 + m0.y, x1 + m1.y, x2 + m2.y);
            const float n2 = lse3(x0 + m0.z, x1 + m1.z, x2 + m2.z);
            x0 = n0; x1 = n1; x2 = n2;
        }

        const float logz = lse3(x0 + sp0, x1 + sp1, x2 + sp2);
        const int y0 = yb[0], yl = yb[NS - 1];
        const float seq = sct + ((y0 == 0) ? st0 : ((y0 == 1) ? st1 : st2))
                              + ((yl == 0) ? sp0 : ((yl == 1) ? sp1 : sp2));
        atomicAdd(loss_out, -(seq - logz) / (float)NB);
    }
}

extern "C" void kernel_launch(void* const* d_in, const int* in_sizes, int n_in,
                              void* d_out, int out_size, void* d_ws, size_t ws_size,
                              hipStream_t stream)
{
    const float* x      = (const float*)d_in[0];
    const int*   y      = (const int*)d_in[1];
    const float* W      = (const float*)d_in[2];
    const float* bias   = (const float*)d_in[3];
    const float* trans  = (const float*)d_in[4];
    const float* startt = (const float*)d_in[5];
    const float* stopt  = (const float*)d_in[6];

    float* out      = (float*)d_out;
    float* loss_out = out + (size_t)NB * NS * NT;

    pred_kernel<<<1024, 256, 0, stream>>>(x, W, bias, out, loss_out);
    crf_kernel<<<NB, 192, 0, stream>>>(out, y, trans, startt, stopt, loss_out);
}